// Round 3
// baseline (465.837 us; speedup 1.0000x reference)
//
#include <hip/hip_runtime.h>
#include <math.h>

#define D_IN   4096
#define D_OUT  4096
#define M_ROWS 8192          // B*S = 4*2048
#define RANK   8
#define SCALING 2.0f
#define EPS_N  1e-8f

// Non-temporal (no-allocate) helpers for use-once streams (W, x, base, out).
// A, Bm, mag_scale, lx stay default-cached (hot in L2).
typedef float f4_t __attribute__((ext_vector_type(4)));

__device__ __forceinline__ f4_t ntl4(const float* p) {
    return __builtin_nontemporal_load((const f4_t*)p);
}
__device__ __forceinline__ void nts4(float* p, f4_t v) {
    __builtin_nontemporal_store(v, (f4_t*)p);
}

// ===========================================================================
// SPLIT PATH
// ===========================================================================
// k_pre: blocks [0,2048)      -> magscale rows {2b, 2b+1}
//        blocks [2048,4096)   -> lx rows {4*(b-2048) .. +3}
// Each thread owns 16 contiguous floats per row via 4 independent float4
// loads (i = t*4 + k*1024), then a block-wide reduction. 16 blocks/CU.
// ---------------------------------------------------------------------------
__global__ __launch_bounds__(256, 4) void k_pre(
    const float* __restrict__ W,     // [D_OUT, D_IN]
    const float* __restrict__ x,     // [M_ROWS, D_IN]
    const float* __restrict__ A,     // [RANK, D_IN]
    const float* __restrict__ Bl,    // [D_OUT, RANK]
    const float* __restrict__ mag,   // [D_OUT]
    float* __restrict__ mag_scale,   // [D_OUT]
    float* __restrict__ Bm,          // [D_OUT, RANK]
    float* __restrict__ lx)          // [M_ROWS, RANK]
{
    const int t    = threadIdx.x;
    const int wave = t >> 6;
    const int lane = t & 63;

    __shared__ float red[4][4][RANK];   // [wave][g][r] partials (512 B)

    if (blockIdx.x < 2048) {
        // ---------------- magscale: rows o0, o0+1 --------------------------
        const int o0 = blockIdx.x * 2;
        const float* W0 = W + (size_t)o0 * D_IN;
        const float* W1 = W0 + D_IN;

        float b0[RANK], b1[RANK];
#pragma unroll
        for (int r = 0; r < RANK; ++r) {
            b0[r] = Bl[o0 * RANK + r];
            b1[r] = Bl[(o0 + 1) * RANK + r];
        }

        float acc0 = 0.f, acc1 = 0.f;
#pragma unroll
        for (int k = 0; k < 4; ++k) {
            const int i = t * 4 + k * 1024;
            f4_t w0 = ntl4(W0 + i);
            f4_t w1 = ntl4(W1 + i);
            float4 a4[RANK];
#pragma unroll
            for (int r = 0; r < RANK; ++r)
                a4[r] = *(const float4*)(A + r * D_IN + i);

            float d0x = 0.f, d0y = 0.f, d0z = 0.f, d0w = 0.f;
            float d1x = 0.f, d1y = 0.f, d1z = 0.f, d1w = 0.f;
#pragma unroll
            for (int r = 0; r < RANK; ++r) {
                d0x += b0[r] * a4[r].x; d0y += b0[r] * a4[r].y;
                d0z += b0[r] * a4[r].z; d0w += b0[r] * a4[r].w;
                d1x += b1[r] * a4[r].x; d1y += b1[r] * a4[r].y;
                d1z += b1[r] * a4[r].z; d1w += b1[r] * a4[r].w;
            }
            float v;
            v = w0.x + SCALING * d0x; acc0 += v * v;
            v = w0.y + SCALING * d0y; acc0 += v * v;
            v = w0.z + SCALING * d0z; acc0 += v * v;
            v = w0.w + SCALING * d0w; acc0 += v * v;
            v = w1.x + SCALING * d1x; acc1 += v * v;
            v = w1.y + SCALING * d1y; acc1 += v * v;
            v = w1.z + SCALING * d1z; acc1 += v * v;
            v = w1.w + SCALING * d1w; acc1 += v * v;
        }
#pragma unroll
        for (int off = 32; off > 0; off >>= 1) {
            acc0 += __shfl_down(acc0, off, 64);
            acc1 += __shfl_down(acc1, off, 64);
        }
        if (lane == 0) { red[wave][0][0] = acc0; red[wave][0][1] = acc1; }
        __syncthreads();
        if (t == 0) {
            float s0 = red[0][0][0] + red[1][0][0] + red[2][0][0] + red[3][0][0];
            float s1 = red[0][0][1] + red[1][0][1] + red[2][0][1] + red[3][0][1];
            float ms0 = mag[o0]     / (sqrtf(s0) + EPS_N);
            float ms1 = mag[o0 + 1] / (sqrtf(s1) + EPS_N);
            mag_scale[o0]     = ms0;
            mag_scale[o0 + 1] = ms1;
            float4 v0, v1, v2, v3;
            v0.x = SCALING * b0[0] * ms0; v0.y = SCALING * b0[1] * ms0;
            v0.z = SCALING * b0[2] * ms0; v0.w = SCALING * b0[3] * ms0;
            v1.x = SCALING * b0[4] * ms0; v1.y = SCALING * b0[5] * ms0;
            v1.z = SCALING * b0[6] * ms0; v1.w = SCALING * b0[7] * ms0;
            v2.x = SCALING * b1[0] * ms1; v2.y = SCALING * b1[1] * ms1;
            v2.z = SCALING * b1[2] * ms1; v2.w = SCALING * b1[3] * ms1;
            v3.x = SCALING * b1[4] * ms1; v3.y = SCALING * b1[5] * ms1;
            v3.z = SCALING * b1[6] * ms1; v3.w = SCALING * b1[7] * ms1;
            *(float4*)(Bm + (size_t)o0 * RANK)           = v0;
            *(float4*)(Bm + (size_t)o0 * RANK + 4)       = v1;
            *(float4*)(Bm + (size_t)(o0 + 1) * RANK)     = v2;
            *(float4*)(Bm + (size_t)(o0 + 1) * RANK + 4) = v3;
        }
    } else {
        // ---------------- lx: rows m0 .. m0+3 ------------------------------
        const int m0 = (blockIdx.x - 2048) * 4;
        const float* x0 = x + (size_t)m0 * D_IN;

        float acc[4][RANK];
#pragma unroll
        for (int g = 0; g < 4; ++g)
#pragma unroll
            for (int r = 0; r < RANK; ++r) acc[g][r] = 0.f;

#pragma unroll
        for (int k = 0; k < 4; ++k) {
            const int i = t * 4 + k * 1024;
            float4 a4[RANK];
#pragma unroll
            for (int r = 0; r < RANK; ++r)
                a4[r] = *(const float4*)(A + r * D_IN + i);
#pragma unroll
            for (int g = 0; g < 4; ++g) {
                f4_t x4 = ntl4(x0 + (size_t)g * D_IN + i);
#pragma unroll
                for (int r = 0; r < RANK; ++r)
                    acc[g][r] += x4.x * a4[r].x + x4.y * a4[r].y +
                                 x4.z * a4[r].z + x4.w * a4[r].w;
            }
        }
#pragma unroll
        for (int g = 0; g < 4; ++g) {
#pragma unroll
            for (int r = 0; r < RANK; ++r) {
                float v = acc[g][r];
#pragma unroll
                for (int off = 32; off > 0; off >>= 1)
                    v += __shfl_down(v, off, 64);
                if (lane == 0) red[wave][g][r] = v;
            }
        }
        __syncthreads();
        if (t < 32) {                       // g = t>>3, r = t&7
            const int g = t >> 3, r = t & 7;
            float v = red[0][g][r] + red[1][g][r] + red[2][g][r] + red[3][g][r];
            lx[(size_t)(m0 + g) * RANK + r] = v;
        }
    }
}

// ---------------------------------------------------------------------------
// k_epi: pure streaming epilogue. Block = (32 m-rows) x (1024-wide o-tile).
// grid = 256*4 = 1024 blocks. Per thread: bm[4][8]+ms4 in regs; per group of
// 8 rows: 8 NT base loads batched in flight, then compute + NT store.
// ---------------------------------------------------------------------------
#define EMT 32

__global__ __launch_bounds__(256, 4) void k_epi(
    const float* __restrict__ base,       // [M_ROWS, D_OUT]
    const float* __restrict__ lx,         // [M_ROWS, RANK]
    const float* __restrict__ Bm,         // [D_OUT, RANK]
    const float* __restrict__ mag_scale,  // [D_OUT]
    float* __restrict__ out)              // [M_ROWS, D_OUT]
{
    const int t    = threadIdx.x;
    const int mb   = (blockIdx.x >> 2) * EMT;
    const int tile = blockIdx.x & 3;
    const int o    = tile * 1024 + t * 4;

    __shared__ float slx[EMT][RANK];
    slx[t >> 3][t & 7] = lx[(size_t)(mb + (t >> 3)) * RANK + (t & 7)];

    const float4 ms4 = *(const float4*)(mag_scale + o);
    float bm[4][RANK];
#pragma unroll
    for (int j = 0; j < 4; ++j) {
        float4 lo = *(const float4*)(Bm + (size_t)(o + j) * RANK);
        float4 hi = *(const float4*)(Bm + (size_t)(o + j) * RANK + 4);
        bm[j][0] = lo.x; bm[j][1] = lo.y; bm[j][2] = lo.z; bm[j][3] = lo.w;
        bm[j][4] = hi.x; bm[j][5] = hi.y; bm[j][6] = hi.z; bm[j][7] = hi.w;
    }
    __syncthreads();

    for (int mi0 = 0; mi0 < EMT; mi0 += 8) {
        f4_t b4[8];
#pragma unroll
        for (int j = 0; j < 8; ++j)
            b4[j] = ntl4(base + (size_t)(mb + mi0 + j) * D_OUT + o);
#pragma unroll
        for (int j = 0; j < 8; ++j) {
            const int mi = mi0 + j;
            float4 llo = *(const float4*)&slx[mi][0];
            float4 lhi = *(const float4*)&slx[mi][4];
            float l[RANK] = { llo.x, llo.y, llo.z, llo.w,
                              lhi.x, lhi.y, lhi.z, lhi.w };
            float rx = b4[j].x * ms4.x;
            float ry = b4[j].y * ms4.y;
            float rz = b4[j].z * ms4.z;
            float rw = b4[j].w * ms4.w;
#pragma unroll
            for (int r = 0; r < RANK; ++r) {
                rx += l[r] * bm[0][r];
                ry += l[r] * bm[1][r];
                rz += l[r] * bm[2][r];
                rw += l[r] * bm[3][r];
            }
            f4_t res; res.x = rx; res.y = ry; res.z = rz; res.w = rw;
            nts4(out + (size_t)(mb + mi) * D_OUT + o, res);
        }
    }
}

// ===========================================================================
// FALLBACK PATH (R2 kernels, known-good) — used only if ws too small for lx.
// ===========================================================================
__global__ __launch_bounds__(256, 2) void k_magscale(
    const float* __restrict__ W, const float* __restrict__ A,
    const float* __restrict__ Bl, const float* __restrict__ mag,
    float* __restrict__ mag_scale, float* __restrict__ Bm)
{
    const int wave = threadIdx.x >> 6;
    const int lane = threadIdx.x & 63;
    const int o0 = blockIdx.x * 8 + wave * 2;
    const float* W0 = W + (size_t)o0 * D_IN;
    const float* W1 = W0 + D_IN;

    float b0[RANK], b1[RANK];
#pragma unroll
    for (int r = 0; r < RANK; ++r) {
        b0[r] = Bl[o0 * RANK + r];
        b1[r] = Bl[(o0 + 1) * RANK + r];
    }
    float acc0 = 0.f, acc1 = 0.f;
    for (int i = lane * 4; i < D_IN; i += 256) {
        float4 a4[RANK];
#pragma unroll
        for (int r = 0; r < RANK; ++r)
            a4[r] = *(const float4*)(A + r * D_IN + i);
        f4_t w0 = ntl4(W0 + i);
        f4_t w1 = ntl4(W1 + i);
        float d0x = 0.f, d0y = 0.f, d0z = 0.f, d0w = 0.f;
        float d1x = 0.f, d1y = 0.f, d1z = 0.f, d1w = 0.f;
#pragma unroll
        for (int r = 0; r < RANK; ++r) {
            d0x += b0[r] * a4[r].x; d0y += b0[r] * a4[r].y;
            d0z += b0[r] * a4[r].z; d0w += b0[r] * a4[r].w;
            d1x += b1[r] * a4[r].x; d1y += b1[r] * a4[r].y;
            d1z += b1[r] * a4[r].z; d1w += b1[r] * a4[r].w;
        }
        float v;
        v = w0.x + SCALING * d0x; acc0 += v * v;
        v = w0.y + SCALING * d0y; acc0 += v * v;
        v = w0.z + SCALING * d0z; acc0 += v * v;
        v = w0.w + SCALING * d0w; acc0 += v * v;
        v = w1.x + SCALING * d1x; acc1 += v * v;
        v = w1.y + SCALING * d1y; acc1 += v * v;
        v = w1.z + SCALING * d1z; acc1 += v * v;
        v = w1.w + SCALING * d1w; acc1 += v * v;
    }
#pragma unroll
    for (int off = 32; off > 0; off >>= 1) {
        acc0 += __shfl_down(acc0, off, 64);
        acc1 += __shfl_down(acc1, off, 64);
    }
    if (lane == 0) {
        float ms0 = mag[o0] / (sqrtf(acc0) + EPS_N);
        float ms1 = mag[o0 + 1] / (sqrtf(acc1) + EPS_N);
        mag_scale[o0] = ms0;
        mag_scale[o0 + 1] = ms1;
#pragma unroll
        for (int r = 0; r < RANK; ++r) {
            Bm[o0 * RANK + r]       = SCALING * b0[r] * ms0;
            Bm[(o0 + 1) * RANK + r] = SCALING * b1[r] * ms1;
        }
    }
}

#define MT 16
__global__ __launch_bounds__(256, 2) void k_fused(
    const float* __restrict__ x, const float* __restrict__ A,
    const float* __restrict__ base, const float* __restrict__ Bm,
    const float* __restrict__ mag_scale, float* __restrict__ out)
{
    const int wave = threadIdx.x >> 6;
    const int lane = threadIdx.x & 63;
    const int mb = blockIdx.x * MT;
    __shared__ float slx[MT][RANK];

    const float* x0 = x + (size_t)(mb + wave * 4) * D_IN;
    float acc[4][RANK];
#pragma unroll
    for (int g = 0; g < 4; ++g)
#pragma unroll
        for (int r = 0; r < RANK; ++r) acc[g][r] = 0.f;

    for (int i = lane * 4; i < D_IN; i += 256) {
        float4 a4[RANK];
#pragma unroll
        for (int r = 0; r < RANK; ++r)
            a4[r] = *(const float4*)(A + r * D_IN + i);
#pragma unroll
        for (int g = 0; g < 4; ++g) {
            f4_t x4 = ntl4(x0 + (size_t)g * D_IN + i);
#pragma unroll
            for (int r = 0; r < RANK; ++r)
                acc[g][r] += x4.x * a4[r].x + x4.y * a4[r].y +
                             x4.z * a4[r].z + x4.w * a4[r].w;
        }
    }
#pragma unroll
    for (int g = 0; g < 4; ++g) {
#pragma unroll
        for (int r = 0; r < RANK; ++r) {
            float v = acc[g][r];
#pragma unroll
            for (int off = 32; off > 0; off >>= 1)
                v += __shfl_down(v, off, 64);
            if (lane == 0) slx[wave * 4 + g][r] = v;
        }
    }
    __syncthreads();

#pragma unroll
    for (int tile = 0; tile < 4; ++tile) {
        const int o = tile * 1024 + threadIdx.x * 4;
        const float4 ms4 = *(const float4*)(mag_scale + o);
        float bm[4][RANK];
#pragma unroll
        for (int j = 0; j < 4; ++j) {
            float4 lo = *(const float4*)(Bm + (size_t)(o + j) * RANK);
            float4 hi = *(const float4*)(Bm + (size_t)(o + j) * RANK + 4);
            bm[j][0] = lo.x; bm[j][1] = lo.y; bm[j][2] = lo.z; bm[j][3] = lo.w;
            bm[j][4] = hi.x; bm[j][5] = hi.y; bm[j][6] = hi.z; bm[j][7] = hi.w;
        }
        for (int mi = 0; mi < MT; ++mi) {
            const size_t row = (size_t)(mb + mi) * D_OUT + o;
            f4_t b4 = ntl4(base + row);
            float l[RANK];
#pragma unroll
            for (int r = 0; r < RANK; ++r) l[r] = slx[mi][r];
            float rx = b4.x * ms4.x;
            float ry = b4.y * ms4.y;
            float rz = b4.z * ms4.z;
            float rw = b4.w * ms4.w;
#pragma unroll
            for (int r = 0; r < RANK; ++r) {
                rx += l[r] * bm[0][r];
                ry += l[r] * bm[1][r];
                rz += l[r] * bm[2][r];
                rw += l[r] * bm[3][r];
            }
            f4_t res; res.x = rx; res.y = ry; res.z = rz; res.w = rw;
            nts4(out + row, res);
        }
    }
}

// ---------------------------------------------------------------------------
extern "C" void kernel_launch(void* const* d_in, const int* in_sizes, int n_in,
                              void* d_out, int out_size, void* d_ws, size_t ws_size,
                              hipStream_t stream) {
    const float* x        = (const float*)d_in[0];  // [4,2048,4096]
    const float* base_out = (const float*)d_in[1];  // [4,2048,4096]
    const float* base_w   = (const float*)d_in[2];  // [4096,4096]
    const float* lora_A   = (const float*)d_in[3];  // [8,4096]
    const float* lora_B   = (const float*)d_in[4];  // [4096,8]
    const float* mag      = (const float*)d_in[5];  // [4096]
    float* out = (float*)d_out;

    float* mag_scale = (float*)d_ws;                // 4096 f
    float* Bm        = mag_scale + D_OUT;           // 4096*8 f
    float* lx        = Bm + (size_t)D_OUT * RANK;   // 8192*8 f

    const size_t need = (size_t)(D_OUT + D_OUT * RANK + M_ROWS * RANK) * sizeof(float);
    if (ws_size >= need) {
        k_pre<<<4096, 256, 0, stream>>>(base_w, x, lora_A, lora_B, mag,
                                        mag_scale, Bm, lx);
        k_epi<<<(M_ROWS / EMT) * 4, 256, 0, stream>>>(base_out, lx, Bm,
                                                      mag_scale, out);
    } else {
        k_magscale<<<D_OUT / 8, 256, 0, stream>>>(base_w, lora_A, lora_B, mag,
                                                  mag_scale, Bm);
        k_fused<<<M_ROWS / MT, 256, 0, stream>>>(x, lora_A, base_out, Bm,
                                                 mag_scale, out);
    }
}